// Round 1
// 826.272 us; speedup vs baseline: 1.0268x; 1.0268x over previous
//
#include <hip/hip_runtime.h>
#include <hip/hip_bf16.h>
#include <math.h>

#define V_LEAVES 1048576
#define EMB 128
#define DEPTH 20

// 16 lanes per batch element; each lane holds 8 floats (2 x float4) of the
// 128-dim embedding. 256-thread blocks -> 16 elements per block.
//
// R1 restructure: the old loop kept ~1 hsoftmax row in flight per element and
// serialized 20x (load-latency -> 4-deep shfl chain -> log1pf libm). Now:
//   * depths processed in 5 chunks of 4; all 4 rows of a chunk load
//     concurrently, and the NEXT chunk's 4 rows prefetch while we reduce
//     (double buffer) -> 4-8 rows in flight per element.
//   * merged butterfly: 4 partial dots reduced across the 16-lane group in
//     5 shuffles (was 16); lane-role (sl&3) owns depth 4c+(sl&3).
//   * softplus via native v_exp/v_log: ln2*log2(1+e) instead of log1pf.
__global__ __launch_bounds__(256, 4) void deepwalk_hsm_kernel(
    const float* __restrict__ emb_table,   // [V, 128]
    const float* __restrict__ hsoftmax,    // [V-1, 128]
    const int*   __restrict__ u,           // [B]
    const int*   __restrict__ v,           // [B]
    float*       __restrict__ out,         // [B]
    int batch)
{
    const int tid  = blockIdx.x * blockDim.x + threadIdx.x;
    const int elem = tid >> 4;        // batch element handled by this 16-lane group
    const int sl   = tid & 15;        // sub-lane within the group
    if (elem >= batch) return;

    // This group's slice of v's embedding: 8 consecutive floats per lane.
    const int vi = v[elem];
    const float4* vrow = (const float4*)(emb_table) + (unsigned)vi * 32u;
    const float4 ve0 = vrow[sl * 2 + 0];
    const float4 ve1 = vrow[sl * 2 + 1];

    // n' = heap_index(leaf) + 1 = V + u. For step d (leaf->root):
    //   parent_d  = (n' >> (d+1)) - 1   (0-indexed inner node)
    //   is_left_d = ((n' >> d) & 1) == 0
    // All addresses derive from n' alone -> every row load is independent.
    const unsigned np = (unsigned)V_LEAVES + (unsigned)u[elem];

    const float4* hbase = (const float4*)hsoftmax;

    float4 hA[4][2], hB[4][2];

    // Prologue: load chunk 0 (depths 0..3) into hA — 4 rows in flight at once.
#pragma unroll
    for (int k = 0; k < 4; ++k) {
        const unsigned pn = (np >> (k + 1)) - 1u;
        const float4* row = hbase + pn * 32u;
        hA[k][0] = row[sl * 2 + 0];
        hA[k][1] = row[sl * 2 + 1];
    }

    float loss = 0.0f;
    const float LN2 = 0.6931471805599453f;

#pragma unroll
    for (int c = 0; c < 5; ++c) {
        // Prefetch next chunk's 4 rows into the other buffer (independent of
        // this chunk's compute; compiler issues these before the vmcnt wait
        // on the current buffer).
        if (c < 4) {
#pragma unroll
            for (int k = 0; k < 4; ++k) {
                const int dn = 4 * (c + 1) + k;
                const unsigned pn = (np >> (dn + 1)) - 1u;
                const float4* row = hbase + pn * 32u;
                float4 (&dst)[4][2] = (c & 1) ? hA : hB;   // c is unroll-constant
                dst[k][0] = row[sl * 2 + 0];
                dst[k][1] = row[sl * 2 + 1];
            }
        }

        float4 (&h)[4][2] = (c & 1) ? hB : hA;             // c is unroll-constant

        // Per-lane partial dots for the 4 depths of this chunk.
        float p[4];
#pragma unroll
        for (int k = 0; k < 4; ++k) {
            const float4 c0 = h[k][0];
            const float4 c1 = h[k][1];
            p[k] = c0.x * ve0.x + c0.y * ve0.y + c0.z * ve0.z + c0.w * ve0.w
                 + c1.x * ve1.x + c1.y * ve1.y + c1.z * ve1.z + c1.w * ve1.w;
        }

        // Merged butterfly: reduce p[0..3] across 16 lanes in 5 shuffles.
        // After this, lane role j = (sl&3) holds the full 128-dot of depth 4c+j.
        const int r1 = sl & 1;
        float a  = r1 ? p[1] : p[0];
        float b  = r1 ? p[0] : p[1];
        a += __shfl_xor(b, 1, 64);
        float e  = r1 ? p[3] : p[2];
        float f  = r1 ? p[2] : p[3];
        e += __shfl_xor(f, 1, 64);
        const int r2 = sl & 2;
        float r  = r2 ? e : a;
        float s  = r2 ? a : e;
        r += __shfl_xor(s, 2, 64);
        r += __shfl_xor(r, 4, 64);
        r += __shfl_xor(r, 8, 64);

        const int d = 4 * c + (sl & 3);
        const bool is_left = ((np >> d) & 1u) == 0u;
        const float x  = is_left ? r : -r;
        const float ax = fabsf(x);
        // -log(sigmoid(x)) = max(-x,0) + log1p(exp(-|x|))
        //                  = max(-x,0) + ln2 * log2(1 + exp(-|x|))
        loss += fmaxf(-x, 0.0f) + LN2 * __log2f(1.0f + __expf(-ax));
    }

    // Each lane accumulated the losses of its role's 5 depths; roles repeat
    // mod 4 across the 16-lane group -> 2 shuffles combine the 4 roles.
    loss += __shfl_xor(loss, 1, 64);
    loss += __shfl_xor(loss, 2, 64);

    if (sl == 0) out[elem] = loss;
}

extern "C" void kernel_launch(void* const* d_in, const int* in_sizes, int n_in,
                              void* d_out, int out_size, void* d_ws, size_t ws_size,
                              hipStream_t stream) {
    const float* emb_table = (const float*)d_in[0];
    const float* hsoftmax  = (const float*)d_in[1];
    const int*   u         = (const int*)d_in[2];
    const int*   v         = (const int*)d_in[3];
    float*       out       = (float*)d_out;

    const int batch = in_sizes[2];            // 65536
    const int threads = batch * 16;           // 16 lanes per element
    const int block = 256;
    const int grid = (threads + block - 1) / block;

    deepwalk_hsm_kernel<<<grid, block, 0, stream>>>(
        emb_table, hsoftmax, u, v, out, batch);
}